// Round 5
// baseline (1838.242 us; speedup 1.0000x reference)
//
#include <hip/hip_runtime.h>
#include <math.h>

#define N_NODES 100000
#define N_EDGES 1600000
#define N_B 64
#define D_IN 64
#define D_HID 128
#define D_OUT 128
#define K_ITER 16
#define LN_EPS 1e-5f

typedef short s8v __attribute__((ext_vector_type(8)));
typedef float f4v __attribute__((ext_vector_type(4)));

__device__ __forceinline__ float gelu_f(float x) {
    return 0.5f * x * (1.0f + erff(0.70710678118654752440f * x));
}

__device__ __forceinline__ float ubx(unsigned u) { return __uint_as_float(u << 16); }
__device__ __forceinline__ float uby(unsigned u) { return __uint_as_float(u & 0xffff0000u); }

__device__ __forceinline__ unsigned short bf_rne(float x) {
    unsigned u = __float_as_uint(x);
    u += 0x7fffu + ((u >> 16) & 1u);
    return (unsigned short)(u >> 16);
}
__device__ __forceinline__ float bf_f(unsigned short s) {
    return __uint_as_float(((unsigned)s) << 16);
}
__device__ __forceinline__ unsigned pack_bf2(float a, float b) {
    return (unsigned)bf_rne(a) | (((unsigned)bf_rne(b)) << 16);
}

// ---------------- CSR build ----------------

__global__ __launch_bounds__(256) void hist_kernel(const int* __restrict__ dst, int* __restrict__ counts) {
    int e = blockIdx.x * 256 + threadIdx.x;
    if (e < N_EDGES) atomicAdd(&counts[dst[e]], 1);
}

__global__ __launch_bounds__(256) void deg_kernel(const int* __restrict__ counts,
                                                  float* __restrict__ dis, float* __restrict__ selfw,
                                                  float* __restrict__ rsq) {
    int i = blockIdx.x * 256 + threadIdx.x;
    if (i < N_NODES) {
        float d = (float)(counts[i] + 1);
        dis[i] = 1.0f / sqrtf(d);
        selfw[i] = 1.0f / d;
        rsq[i] = sqrtf(d);
    }
}

__global__ __launch_bounds__(1024) void scan1(const int* __restrict__ counts, int* __restrict__ rp,
                                              int* __restrict__ bsum) {
    __shared__ int tmp[1024];
    int t = threadIdx.x;
    int idx = blockIdx.x * 1024 + t;
    int v = (idx < N_NODES) ? counts[idx] : 0;
    tmp[t] = v;
    __syncthreads();
    for (int o = 1; o < 1024; o <<= 1) {
        int add = (t >= o) ? tmp[t - o] : 0;
        __syncthreads();
        tmp[t] += add;
        __syncthreads();
    }
    if (idx < N_NODES) rp[idx] = tmp[t] - v;   // exclusive
    if (t == 1023) bsum[blockIdx.x] = tmp[t];
}

__global__ void scan2(int* bsum, int nb) {
    if (threadIdx.x == 0 && blockIdx.x == 0) {
        int acc = 0;
        for (int i = 0; i < nb; i++) { int v = bsum[i]; bsum[i] = acc; acc += v; }
    }
}

__global__ __launch_bounds__(1024) void scan3(int* __restrict__ rp, const int* __restrict__ bsum,
                                              int* __restrict__ cursor) {
    int t = threadIdx.x;
    int idx = blockIdx.x * 1024 + t;
    if (idx < N_NODES) {
        int v = rp[idx] + bsum[blockIdx.x];
        rp[idx] = v;
        cursor[idx] = v;
    }
    if (idx == 0) rp[N_NODES] = N_EDGES;
}

// Single 16B store per edge: {src, ea.x, ea.y, 0}. One cache line touched per edge.
__global__ __launch_bounds__(256) void scatter_kernel(const int* __restrict__ src, const int* __restrict__ dst,
                                                      const float* __restrict__ ea,
                                                      int* __restrict__ cursor, int4* __restrict__ edata) {
    int e = blockIdx.x * 256 + threadIdx.x;
    if (e >= N_EDGES) return;
    int s = src[e], d = dst[e];
    int pos = atomicAdd(&cursor[d], 1);
    float2 e2 = ((const float2*)ea)[e];
    int4 v;
    v.x = s;
    v.y = __float_as_int(e2.x);
    v.z = __float_as_int(e2.y);
    v.w = 0;
    edata[pos] = v;
}

// Compact 4B/edge src stream for APPNP (coalesced read+write).
__global__ __launch_bounds__(256) void split_kernel(const int4* __restrict__ edata, int* __restrict__ esrc) {
    int e = blockIdx.x * 256 + threadIdx.x;
    if (e < N_EDGES) esrc[e] = edata[e].x;
}

// x (f32 [N,64]) -> bf16 copy for conv1 message gathers (halves gather bytes).
__global__ __launch_bounds__(256) void x_to_bf(const float4* __restrict__ x4, uint2* __restrict__ xb2) {
    int i = blockIdx.x * 256 + threadIdx.x;
    if (i < N_NODES * 16) {
        float4 v = x4[i];
        uint2 o;
        o.x = pack_bf2(v.x, v.y);
        o.y = pack_bf2(v.z, v.w);
        xb2[i] = o;
    }
}

// ---------------- GINE gathers (round-3 form: full-wave rows, wave-uniform indices) ----------------

// Self term from f32 x; gathered messages from bf16 x copy (128 B/row).
__global__ __launch_bounds__(256) void conv1_gather(const float* __restrict__ x,
                                                    const unsigned short* __restrict__ xb,
                                                    const int* __restrict__ rp,
                                                    const int4* __restrict__ edata,
                                                    const float* __restrict__ We1, const float* __restrict__ be1,
                                                    float* __restrict__ out) {
    int gw = (blockIdx.x * 256 + threadIdx.x) >> 6;
    if (gw >= N_NODES) return;
    int lane = threadIdx.x & 63;
    float w0 = We1[lane], w1 = We1[64 + lane], bb = be1[lane];
    float acc = x[(size_t)gw * 64 + lane];
    int j = rp[gw], jend = rp[gw + 1];
    for (; j + 8 <= jend; j += 8) {
        int4 e0 = edata[j], e1 = edata[j + 1], e2 = edata[j + 2], e3 = edata[j + 3];
        int4 e4 = edata[j + 4], e5 = edata[j + 5], e6 = edata[j + 6], e7 = edata[j + 7];
        unsigned short v0 = xb[(size_t)e0.x * 64 + lane];
        unsigned short v1 = xb[(size_t)e1.x * 64 + lane];
        unsigned short v2 = xb[(size_t)e2.x * 64 + lane];
        unsigned short v3 = xb[(size_t)e3.x * 64 + lane];
        unsigned short v4 = xb[(size_t)e4.x * 64 + lane];
        unsigned short v5 = xb[(size_t)e5.x * 64 + lane];
        unsigned short v6 = xb[(size_t)e6.x * 64 + lane];
        unsigned short v7 = xb[(size_t)e7.x * 64 + lane];
        acc += fmaxf(bf_f(v0) + __int_as_float(e0.y) * w0 + __int_as_float(e0.z) * w1 + bb, 0.0f);
        acc += fmaxf(bf_f(v1) + __int_as_float(e1.y) * w0 + __int_as_float(e1.z) * w1 + bb, 0.0f);
        acc += fmaxf(bf_f(v2) + __int_as_float(e2.y) * w0 + __int_as_float(e2.z) * w1 + bb, 0.0f);
        acc += fmaxf(bf_f(v3) + __int_as_float(e3.y) * w0 + __int_as_float(e3.z) * w1 + bb, 0.0f);
        acc += fmaxf(bf_f(v4) + __int_as_float(e4.y) * w0 + __int_as_float(e4.z) * w1 + bb, 0.0f);
        acc += fmaxf(bf_f(v5) + __int_as_float(e5.y) * w0 + __int_as_float(e5.z) * w1 + bb, 0.0f);
        acc += fmaxf(bf_f(v6) + __int_as_float(e6.y) * w0 + __int_as_float(e6.z) * w1 + bb, 0.0f);
        acc += fmaxf(bf_f(v7) + __int_as_float(e7.y) * w0 + __int_as_float(e7.z) * w1 + bb, 0.0f);
    }
    for (; j < jend; j++) {
        int4 e = edata[j];
        unsigned short v = xb[(size_t)e.x * 64 + lane];
        acc += fmaxf(bf_f(v) + __int_as_float(e.y) * w0 + __int_as_float(e.z) * w1 + bb, 0.0f);
    }
    out[(size_t)gw * 64 + lane] = acc;
}

// conv2: self term from f32 h1, gathered messages from bf16 h1 copy.
__global__ __launch_bounds__(256) void conv2_gather(const float* __restrict__ h1f, const unsigned* __restrict__ h1b,
                                                    const int* __restrict__ rp,
                                                    const int4* __restrict__ edata,
                                                    const float* __restrict__ We2, const float* __restrict__ be2,
                                                    float* __restrict__ out) {
    int gw = (blockIdx.x * 256 + threadIdx.x) >> 6;
    if (gw >= N_NODES) return;
    int lane = threadIdx.x & 63;
    int f0 = lane * 2;
    float w00 = We2[f0], w01 = We2[f0 + 1];
    float w10 = We2[128 + f0], w11 = We2[128 + f0 + 1];
    float b0 = be2[f0], b1 = be2[f0 + 1];
    float2 hc = ((const float2*)h1f)[(size_t)gw * 64 + lane];
    float a0 = hc.x, a1 = hc.y;
    int j = rp[gw], jend = rp[gw + 1];
    for (; j + 8 <= jend; j += 8) {
        int4 e0 = edata[j], e1 = edata[j + 1], e2 = edata[j + 2], e3 = edata[j + 3];
        int4 e4 = edata[j + 4], e5 = edata[j + 5], e6 = edata[j + 6], e7 = edata[j + 7];
        unsigned v0 = h1b[(size_t)e0.x * 64 + lane];
        unsigned v1 = h1b[(size_t)e1.x * 64 + lane];
        unsigned v2 = h1b[(size_t)e2.x * 64 + lane];
        unsigned v3 = h1b[(size_t)e3.x * 64 + lane];
        unsigned v4 = h1b[(size_t)e4.x * 64 + lane];
        unsigned v5 = h1b[(size_t)e5.x * 64 + lane];
        unsigned v6 = h1b[(size_t)e6.x * 64 + lane];
        unsigned v7 = h1b[(size_t)e7.x * 64 + lane];
        a0 += fmaxf(ubx(v0) + __int_as_float(e0.y) * w00 + __int_as_float(e0.z) * w10 + b0, 0.0f);
        a1 += fmaxf(uby(v0) + __int_as_float(e0.y) * w01 + __int_as_float(e0.z) * w11 + b1, 0.0f);
        a0 += fmaxf(ubx(v1) + __int_as_float(e1.y) * w00 + __int_as_float(e1.z) * w10 + b0, 0.0f);
        a1 += fmaxf(uby(v1) + __int_as_float(e1.y) * w01 + __int_as_float(e1.z) * w11 + b1, 0.0f);
        a0 += fmaxf(ubx(v2) + __int_as_float(e2.y) * w00 + __int_as_float(e2.z) * w10 + b0, 0.0f);
        a1 += fmaxf(uby(v2) + __int_as_float(e2.y) * w01 + __int_as_float(e2.z) * w11 + b1, 0.0f);
        a0 += fmaxf(ubx(v3) + __int_as_float(e3.y) * w00 + __int_as_float(e3.z) * w10 + b0, 0.0f);
        a1 += fmaxf(uby(v3) + __int_as_float(e3.y) * w01 + __int_as_float(e3.z) * w11 + b1, 0.0f);
        a0 += fmaxf(ubx(v4) + __int_as_float(e4.y) * w00 + __int_as_float(e4.z) * w10 + b0, 0.0f);
        a1 += fmaxf(uby(v4) + __int_as_float(e4.y) * w01 + __int_as_float(e4.z) * w11 + b1, 0.0f);
        a0 += fmaxf(ubx(v5) + __int_as_float(e5.y) * w00 + __int_as_float(e5.z) * w10 + b0, 0.0f);
        a1 += fmaxf(uby(v5) + __int_as_float(e5.y) * w01 + __int_as_float(e5.z) * w11 + b1, 0.0f);
        a0 += fmaxf(ubx(v6) + __int_as_float(e6.y) * w00 + __int_as_float(e6.z) * w10 + b0, 0.0f);
        a1 += fmaxf(uby(v6) + __int_as_float(e6.y) * w01 + __int_as_float(e6.z) * w11 + b1, 0.0f);
        a0 += fmaxf(ubx(v7) + __int_as_float(e7.y) * w00 + __int_as_float(e7.z) * w10 + b0, 0.0f);
        a1 += fmaxf(uby(v7) + __int_as_float(e7.y) * w01 + __int_as_float(e7.z) * w11 + b1, 0.0f);
    }
    for (; j < jend; j++) {
        int4 e = edata[j];
        unsigned v = h1b[(size_t)e.x * 64 + lane];
        a0 += fmaxf(ubx(v) + __int_as_float(e.y) * w00 + __int_as_float(e.z) * w10 + b0, 0.0f);
        a1 += fmaxf(uby(v) + __int_as_float(e.y) * w01 + __int_as_float(e.z) * w11 + b1, 0.0f);
    }
    out[(size_t)gw * 128 + f0] = a0;
    out[(size_t)gw * 128 + f0 + 1] = a1;
}

// ---------------- MLP layers via MFMA (split-bf16: Ahi*Whi + Ahi*Wlo + Alo*Whi) ----------------
// OMODE: 0 = f32 out only, 1 = f32 + bf16 copy, 2 = bf16 only.
// SCALE: multiply bf16 output by uscale[row] (used to emit u0 = dis*h for APPNP).

template <int Kd, bool GELU, bool LN, int OMODE, bool SCALE>
__global__ __launch_bounds__(256) void mlp_mfma(const float* __restrict__ A, const float* __restrict__ W,
                                                const float* __restrict__ bias, const float* __restrict__ g,
                                                const float* __restrict__ bn, float* __restrict__ outf,
                                                unsigned short* __restrict__ outb,
                                                const float* __restrict__ uscale) {
    __shared__ unsigned short sHi[8192];   // 64 k-rows x 128 cols, swizzled
    __shared__ unsigned short sLo[8192];
    int wave = threadIdx.x >> 6, lane = threadIdx.x & 63;
    int quad = lane >> 4, n = lane & 15;
    int rowA = blockIdx.x * 64 + wave * 16 + n;
    int rowAc = (rowA < N_NODES) ? rowA : 0;

    f4v acc[8];
    #pragma unroll
    for (int t = 0; t < 8; t++) acc[t] = (f4v){0.f, 0.f, 0.f, 0.f};

    for (int ph = 0; ph < Kd / 64; ph++) {
        __syncthreads();
        for (int idx = threadIdx.x; idx < 8192; idx += 256) {
            int k = idx >> 7, c = idx & 127;
            float v = W[(size_t)(ph * 64 + k) * 128 + c];
            unsigned short hi = bf_rne(v);
            unsigned short lo = bf_rne(v - bf_f(hi));
            int kk = k >> 5, q = (k >> 3) & 3, j = k & 7, t = c >> 4, nn = c & 15;
            int lidx = ((((kk * 4 + q) * 8 + t) * 16 + nn) << 3) + j;
            sHi[lidx] = hi;
            sLo[lidx] = lo;
        }
        __syncthreads();
        #pragma unroll
        for (int kk = 0; kk < 2; kk++) {
            int k0 = ph * 64 + kk * 32 + quad * 8;
            const float4* ap = (const float4*)(A + (size_t)rowAc * Kd + k0);
            float4 a0 = ap[0], a1 = ap[1];
            float av[8] = {a0.x, a0.y, a0.z, a0.w, a1.x, a1.y, a1.z, a1.w};
            s8v ahi, alo;
            #pragma unroll
            for (int j = 0; j < 8; j++) {
                unsigned short h = bf_rne(av[j]);
                ahi[j] = (short)h;
                alo[j] = (short)bf_rne(av[j] - bf_f(h));
            }
            int base = ((kk * 4 + quad) * 8) * 128;
            #pragma unroll
            for (int t = 0; t < 8; t++) {
                s8v bhi = *(const s8v*)&sHi[base + ((t * 16 + n) << 3)];
                s8v blo = *(const s8v*)&sLo[base + ((t * 16 + n) << 3)];
                acc[t] = __builtin_amdgcn_mfma_f32_16x16x32_bf16(ahi, bhi, acc[t], 0, 0, 0);
                acc[t] = __builtin_amdgcn_mfma_f32_16x16x32_bf16(ahi, blo, acc[t], 0, 0, 0);
                acc[t] = __builtin_amdgcn_mfma_f32_16x16x32_bf16(alo, bhi, acc[t], 0, 0, 0);
            }
        }
    }

    float bcol[8], gcol[8], bncol[8];
    #pragma unroll
    for (int t = 0; t < 8; t++) {
        bcol[t] = bias[t * 16 + n];
        if (LN) { gcol[t] = g[t * 16 + n]; bncol[t] = bn[t * 16 + n]; }
    }
    #pragma unroll
    for (int r = 0; r < 4; r++) {
        int row = blockIdx.x * 64 + wave * 16 + quad * 4 + r;
        float v[8];
        #pragma unroll
        for (int t = 0; t < 8; t++) {
            float x = acc[t][r] + bcol[t];
            v[t] = GELU ? gelu_f(x) : x;
        }
        if (LN) {
            float s = 0.f, q2 = 0.f;
            #pragma unroll
            for (int t = 0; t < 8; t++) { s += v[t]; q2 += v[t] * v[t]; }
            #pragma unroll
            for (int m = 1; m <= 8; m <<= 1) {
                s += __shfl_xor(s, m, 64);
                q2 += __shfl_xor(q2, m, 64);
            }
            float mu = s * (1.0f / 128.0f);
            float rs = rsqrtf(q2 * (1.0f / 128.0f) - mu * mu + LN_EPS);
            #pragma unroll
            for (int t = 0; t < 8; t++) v[t] = (v[t] - mu) * rs * gcol[t] + bncol[t];
        }
        if (row < N_NODES) {
            float us = SCALE ? uscale[row] : 1.0f;
            #pragma unroll
            for (int t = 0; t < 8; t++) {
                if (OMODE != 2) outf[(size_t)row * 128 + t * 16 + n] = v[t];
                if (OMODE >= 1) outb[(size_t)row * 128 + t * 16 + n] = bf_rne(SCALE ? v[t] * us : v[t]);
            }
        }
    }
}

// ---------------- Gate via MFMA: gate = gelu(h@Wg1+bg1)@Wg2 + bg2 ----------------

__global__ __launch_bounds__(256) void gate_mfma(const float* __restrict__ h, const float* __restrict__ Wg1,
                                                 const float* __restrict__ bg1, const float* __restrict__ Wg2,
                                                 const float* __restrict__ bg2, float* __restrict__ gate) {
    __shared__ unsigned short sHi[8192];  // 128 k x 64 cols, swizzled
    __shared__ unsigned short sLo[8192];
    int wave = threadIdx.x >> 6, lane = threadIdx.x & 63;
    int quad = lane >> 4, n = lane & 15;
    for (int idx = threadIdx.x; idx < 8192; idx += 256) {
        int k = idx >> 6, c = idx & 63;
        float v = Wg1[k * 64 + c];
        unsigned short hi = bf_rne(v);
        unsigned short lo = bf_rne(v - bf_f(hi));
        int kk = k >> 5, q = (k >> 3) & 3, j = k & 7, t = c >> 4, nn = c & 15;
        int lidx = ((((kk * 4 + q) * 4 + t) * 16 + nn) << 3) + j;
        sHi[lidx] = hi;
        sLo[lidx] = lo;
    }
    __syncthreads();
    int rowA = blockIdx.x * 64 + wave * 16 + n;
    int rowAc = (rowA < N_NODES) ? rowA : 0;
    f4v acc[4];
    #pragma unroll
    for (int t = 0; t < 4; t++) acc[t] = (f4v){0.f, 0.f, 0.f, 0.f};
    #pragma unroll
    for (int kk = 0; kk < 4; kk++) {
        const float4* ap = (const float4*)(h + (size_t)rowAc * 128 + kk * 32 + quad * 8);
        float4 a0 = ap[0], a1 = ap[1];
        float av[8] = {a0.x, a0.y, a0.z, a0.w, a1.x, a1.y, a1.z, a1.w};
        s8v ahi, alo;
        #pragma unroll
        for (int j = 0; j < 8; j++) {
            unsigned short hh = bf_rne(av[j]);
            ahi[j] = (short)hh;
            alo[j] = (short)bf_rne(av[j] - bf_f(hh));
        }
        int base = ((kk * 4 + quad) * 4) * 128;
        #pragma unroll
        for (int t = 0; t < 4; t++) {
            s8v bhi = *(const s8v*)&sHi[base + ((t * 16 + n) << 3)];
            s8v blo = *(const s8v*)&sLo[base + ((t * 16 + n) << 3)];
            acc[t] = __builtin_amdgcn_mfma_f32_16x16x32_bf16(ahi, bhi, acc[t], 0, 0, 0);
            acc[t] = __builtin_amdgcn_mfma_f32_16x16x32_bf16(ahi, blo, acc[t], 0, 0, 0);
            acc[t] = __builtin_amdgcn_mfma_f32_16x16x32_bf16(alo, bhi, acc[t], 0, 0, 0);
        }
    }
    float b2 = bg2[0];
    float bb[4], vv[4];
    #pragma unroll
    for (int t = 0; t < 4; t++) { bb[t] = bg1[t * 16 + n]; vv[t] = Wg2[t * 16 + n]; }
    #pragma unroll
    for (int r = 0; r < 4; r++) {
        int row = blockIdx.x * 64 + wave * 16 + quad * 4 + r;
        float val = 0.f;
        #pragma unroll
        for (int t = 0; t < 4; t++) val += gelu_f(acc[t][r] + bb[t]) * vv[t];
        #pragma unroll
        for (int m = 1; m <= 8; m <<= 1) val += __shfl_xor(val, m, 64);
        if (n == 0 && row < N_NODES) gate[row] = val + b2;
    }
}

// ---------------- APPNP in scaled space u = dis*h, TWO nodes per wave ----------------
// u'_i = 0.9*selfw_i*(sum_j u_j + u_i) + 0.1*u0_i ; final h = u*rsq.
// One wave owns nodes 2w and 2w+1 with interleaved 4-gather batches from the two
// independent edge streams: 8 rows in flight per wave from two separate dependency
// chains, per-node setup (rp/self/anchor/selfw loads) shared and hoisted so its
// latency hides under the edge loop. Gathers stay full-wave 256B rows with
// wave-uniform src indices (round-4 lesson: divergent indexing costs more than it buys).

#define GA(S)  { unsigned v = hin[(size_t)(S) * 64 + lane]; axA += ubx(v); ayA += uby(v); }
#define GB(S)  { unsigned v = hin[(size_t)(S) * 64 + lane]; axB += ubx(v); ayB += uby(v); }

template <bool LAST>
__global__ __launch_bounds__(256) void appnp_step_u(const unsigned* __restrict__ hin,
                                                    const unsigned* __restrict__ anchor,
                                                    unsigned* __restrict__ hout, float2* __restrict__ houtf,
                                                    const int* __restrict__ rp, const int* __restrict__ esrc,
                                                    const float* __restrict__ selfw,
                                                    const float* __restrict__ rsq) {
    int wid = (blockIdx.x * 256 + threadIdx.x) >> 6;
    int gA = wid * 2;            // N_NODES is even: gB always valid when gA is
    if (gA >= N_NODES) return;
    int gB = gA + 1;
    int lane = threadIdx.x & 63;
    size_t idxA = (size_t)gA * 64 + lane;
    size_t idxB = (size_t)gB * 64 + lane;
    // Hoisted latency loads: self rows, anchor rows, selfw, rp (rp[gA..gA+2] contiguous).
    unsigned hcA = hin[idxA];
    unsigned hcB = hin[idxB];
    unsigned anA = anchor[idxA];
    unsigned anB = anchor[idxB];
    float swA = selfw[gA], swB = selfw[gB];
    int jA = rp[gA], eA = rp[gA + 1], eB = rp[gA + 2];
    int jB = eA;
    float axA = ubx(hcA), ayA = uby(hcA);
    float axB = ubx(hcB), ayB = uby(hcB);
    // Joint loop: 4 gathers per node per iteration, two independent chains.
    while (jA + 4 <= eA && jB + 4 <= eB) {
        int a0 = esrc[jA], a1 = esrc[jA + 1], a2 = esrc[jA + 2], a3 = esrc[jA + 3];
        int b0 = esrc[jB], b1 = esrc[jB + 1], b2 = esrc[jB + 2], b3 = esrc[jB + 3];
        unsigned vA0 = hin[(size_t)a0 * 64 + lane];
        unsigned vA1 = hin[(size_t)a1 * 64 + lane];
        unsigned vA2 = hin[(size_t)a2 * 64 + lane];
        unsigned vA3 = hin[(size_t)a3 * 64 + lane];
        unsigned vB0 = hin[(size_t)b0 * 64 + lane];
        unsigned vB1 = hin[(size_t)b1 * 64 + lane];
        unsigned vB2 = hin[(size_t)b2 * 64 + lane];
        unsigned vB3 = hin[(size_t)b3 * 64 + lane];
        axA += ubx(vA0); ayA += uby(vA0);
        axA += ubx(vA1); ayA += uby(vA1);
        axA += ubx(vA2); ayA += uby(vA2);
        axA += ubx(vA3); ayA += uby(vA3);
        axB += ubx(vB0); ayB += uby(vB0);
        axB += ubx(vB1); ayB += uby(vB1);
        axB += ubx(vB2); ayB += uby(vB2);
        axB += ubx(vB3); ayB += uby(vB3);
        jA += 4; jB += 4;
    }
    // Finish A (8/4/1 ladder).
    for (; jA + 8 <= eA; jA += 8) {
        int a0 = esrc[jA], a1 = esrc[jA + 1], a2 = esrc[jA + 2], a3 = esrc[jA + 3];
        int a4 = esrc[jA + 4], a5 = esrc[jA + 5], a6 = esrc[jA + 6], a7 = esrc[jA + 7];
        GA(a0); GA(a1); GA(a2); GA(a3); GA(a4); GA(a5); GA(a6); GA(a7);
    }
    for (; jA + 4 <= eA; jA += 4) {
        int a0 = esrc[jA], a1 = esrc[jA + 1], a2 = esrc[jA + 2], a3 = esrc[jA + 3];
        GA(a0); GA(a1); GA(a2); GA(a3);
    }
    for (; jA < eA; jA++) { int a0 = esrc[jA]; GA(a0); }
    // Finish B (8/4/1 ladder).
    for (; jB + 8 <= eB; jB += 8) {
        int b0 = esrc[jB], b1 = esrc[jB + 1], b2 = esrc[jB + 2], b3 = esrc[jB + 3];
        int b4 = esrc[jB + 4], b5 = esrc[jB + 5], b6 = esrc[jB + 6], b7 = esrc[jB + 7];
        GB(b0); GB(b1); GB(b2); GB(b3); GB(b4); GB(b5); GB(b6); GB(b7);
    }
    for (; jB + 4 <= eB; jB += 4) {
        int b0 = esrc[jB], b1 = esrc[jB + 1], b2 = esrc[jB + 2], b3 = esrc[jB + 3];
        GB(b0); GB(b1); GB(b2); GB(b3);
    }
    for (; jB < eB; jB++) { int b0 = esrc[jB]; GB(b0); }
    // Combine and write both rows (same arithmetic order as round-3 build).
    float swiA = 0.9f * swA, swiB = 0.9f * swB;
    float oAx = fmaf(swiA, axA, 0.1f * ubx(anA));
    float oAy = fmaf(swiA, ayA, 0.1f * uby(anA));
    float oBx = fmaf(swiB, axB, 0.1f * ubx(anB));
    float oBy = fmaf(swiB, ayB, 0.1f * uby(anB));
    if (LAST) {
        float rqA = rsq[gA], rqB = rsq[gB];
        float2 oA; oA.x = oAx * rqA; oA.y = oAy * rqA;
        float2 oB; oB.x = oBx * rqB; oB.y = oBy * rqB;
        houtf[idxA] = oA;
        houtf[idxB] = oB;
    } else {
        hout[idxA] = pack_bf2(oAx, oAy);
        hout[idxB] = pack_bf2(oBx, oBy);
    }
}

#undef GA
#undef GB

// ---------------- Attentional pooling ----------------

__global__ void seg_begin(const int* __restrict__ batch, int* __restrict__ gbeg) {
    int b = threadIdx.x;
    if (b > N_B) return;
    if (b == N_B) { gbeg[N_B] = N_NODES; return; }
    int lo = 0, hi = N_NODES;
    while (lo < hi) {
        int mid = (lo + hi) >> 1;
        if (batch[mid] < b) lo = mid + 1; else hi = mid;
    }
    gbeg[b] = lo;
}

__global__ __launch_bounds__(256) void seg_max(const float* __restrict__ gate, const int* __restrict__ gbeg,
                                               float* __restrict__ gmax) {
    int b = blockIdx.x;
    int s = gbeg[b], e = gbeg[b + 1];
    float m = -INFINITY;
    for (int i = s + threadIdx.x; i < e; i += 256) m = fmaxf(m, gate[i]);
    for (int o = 32; o > 0; o >>= 1) m = fmaxf(m, __shfl_xor(m, o, 64));
    __shared__ float red[4];
    if ((threadIdx.x & 63) == 0) red[threadIdx.x >> 6] = m;
    __syncthreads();
    if (threadIdx.x == 0) gmax[b] = fmaxf(fmaxf(red[0], red[1]), fmaxf(red[2], red[3]));
}

__global__ __launch_bounds__(256) void seg_sum(const float* __restrict__ gate, const int* __restrict__ gbeg,
                                               const float* __restrict__ gmax, float* __restrict__ gsum) {
    int b = blockIdx.x;
    int s = gbeg[b], e = gbeg[b + 1];
    float m = gmax[b];
    float acc = 0.0f;
    for (int i = s + threadIdx.x; i < e; i += 256) acc += expf(gate[i] - m);
    for (int o = 32; o > 0; o >>= 1) acc += __shfl_xor(acc, o, 64);
    __shared__ float red[4];
    if ((threadIdx.x & 63) == 0) red[threadIdx.x >> 6] = acc;
    __syncthreads();
    if (threadIdx.x == 0) gsum[b] = red[0] + red[1] + red[2] + red[3];
}

// 8 slices per graph; atomicAdd into zero-initialized gout.
__global__ __launch_bounds__(512) void seg_pool(const float* __restrict__ h, const float* __restrict__ gate,
                                                const int* __restrict__ gbeg, const float* __restrict__ gmax,
                                                const float* __restrict__ gsum, float* __restrict__ gout) {
    int b = blockIdx.x >> 3, slice = blockIdx.x & 7;
    int team = threadIdx.x >> 7;
    int f = threadIdx.x & 127;
    int s = gbeg[b], e = gbeg[b + 1];
    float m = gmax[b];
    float inv = (e > s) ? 1.0f / gsum[b] : 0.0f;
    float acc = 0.0f;
    for (int i = s + slice * 4 + team; i < e; i += 32) {
        float a = expf(gate[i] - m) * inv;
        acc = fmaf(a, h[(size_t)i * 128 + f], acc);
    }
    __shared__ float red[4][128];
    red[team][f] = acc;
    __syncthreads();
    if (team == 0) {
        float v = red[0][f] + red[1][f] + red[2][f] + red[3][f];
        atomicAdd(&gout[b * 128 + f], v);
    }
}

// ---------------- host launch ----------------

extern "C" void kernel_launch(void* const* d_in, const int* in_sizes, int n_in,
                              void* d_out, int out_size, void* d_ws, size_t ws_size,
                              hipStream_t stream) {
    const float* x     = (const float*)d_in[0];
    const int*   ei    = (const int*)d_in[1];
    const int*   batch = (const int*)d_in[2];
    const float* ea    = (const float*)d_in[3];
    const float* We1 = (const float*)d_in[4];
    const float* be1 = (const float*)d_in[5];
    const float* W1a = (const float*)d_in[6];
    const float* b1a = (const float*)d_in[7];
    const float* W1b = (const float*)d_in[8];
    const float* b1b = (const float*)d_in[9];
    const float* g1  = (const float*)d_in[10];
    const float* bn1 = (const float*)d_in[11];
    const float* We2 = (const float*)d_in[12];
    const float* be2 = (const float*)d_in[13];
    const float* W2a = (const float*)d_in[14];
    const float* b2a = (const float*)d_in[15];
    const float* W2b = (const float*)d_in[16];
    const float* b2b = (const float*)d_in[17];
    const float* g2  = (const float*)d_in[18];
    const float* bn2 = (const float*)d_in[19];
    const float* Wg1 = (const float*)d_in[20];
    const float* bg1 = (const float*)d_in[21];
    const float* Wg2 = (const float*)d_in[22];
    const float* bg2 = (const float*)d_in[23];

    float* outH = (float*)d_out;                 // [N,128] final h (also used as scratch)
    float* outG = outH + (size_t)N_NODES * 128;  // [B,128] pooled

    char* w = (char*)d_ws;
    auto carve = [&](size_t bytes) {
        void* p = (void*)w;
        w += ((bytes + 255) / 256) * 256;
        return p;
    };
    float*  bufB   = (float*)carve((size_t)N_NODES * 128 * 4);  // 51.2 MB
    float*  bufC   = (float*)carve((size_t)N_NODES * 128 * 4);  // 51.2 MB
    int4*   edata  = (int4*)carve((size_t)N_EDGES * 16);        // 25.6 MB {src, ea.x, ea.y, 0}
    int*    counts = (int*)carve((size_t)N_NODES * 4);
    int*    rp     = (int*)carve((size_t)(N_NODES + 1) * 4);
    int*    cursor = (int*)carve((size_t)N_NODES * 4);
    float*  dis    = (float*)carve((size_t)N_NODES * 4);
    float*  selfw  = (float*)carve((size_t)N_NODES * 4);
    float*  rsq    = (float*)carve((size_t)N_NODES * 4);
    float*  gate   = (float*)carve((size_t)N_NODES * 4);
    int*    bsum   = (int*)carve(128 * 4);
    float*  gmax   = (float*)carve(N_B * 4);
    float*  gsum   = (float*)carve(N_B * 4);
    int*    gbeg   = (int*)carve((N_B + 1) * 4);

    const int* src = ei;
    const int* dst = ei + N_EDGES;

    const int NB_SCAN = (N_NODES + 1023) / 1024;  // 98
    const int EB = (N_EDGES + 255) / 256;
    const int NBLK = (N_NODES + 255) / 256;
    const int WBLK = (N_NODES + 3) / 4;       // one wave per node, 4 waves/block
    const int WBLK2 = (N_NODES / 2 + 3) / 4;  // one wave per 2 nodes (APPNP)
    const int MBLK = (N_NODES + 63) / 64;     // 1563 blocks for mfma kernels

    // Buffer plan (liveness):
    //   xb (bf16 x copy) = bufC[25.6:38.4MB] (pingA region; dead until APPNP)
    //   agg1 = bufB ; t1 = outH ; h1f = bufB (overwrites agg1), h1bf = bufC[0:25.6MB]
    //   agg2 = outH (overwrites t1) ; t2 = bufB (overwrites h1f)
    //   anchor u0 = bufC[0:25.6] (overwrites h1bf) ; pingA = bufC[25.6:51.2] ; pingB = bufB[0:25.6]
    //   esrc = bufB[25.6:32.0] (written by split_kernel after mlp2b reads bufB)
    unsigned short* h1bf  = (unsigned short*)bufC;
    unsigned* ancU  = (unsigned*)bufC;
    unsigned* pingA = ancU + (size_t)N_NODES * 64;
    unsigned* pingB = (unsigned*)bufB;
    unsigned short* xb = (unsigned short*)pingA;   // [N,64] bf16, dead before APPNP starts
    int*      esrc  = (int*)(bufB + (size_t)N_NODES * 64);

    // CSR build
    hipMemsetAsync(counts, 0, (size_t)N_NODES * 4, stream);
    hist_kernel<<<EB, 256, 0, stream>>>(dst, counts);
    deg_kernel<<<NBLK, 256, 0, stream>>>(counts, dis, selfw, rsq);
    scan1<<<NB_SCAN, 1024, 0, stream>>>(counts, rp, bsum);
    scan2<<<1, 64, 0, stream>>>(bsum, NB_SCAN);
    scan3<<<NB_SCAN, 1024, 0, stream>>>(rp, bsum, cursor);
    scatter_kernel<<<EB, 256, 0, stream>>>(src, dst, ea, cursor, edata);
    x_to_bf<<<(N_NODES * 16 + 255) / 256, 256, 0, stream>>>((const float4*)x, (uint2*)xb);

    // conv1
    conv1_gather<<<WBLK, 256, 0, stream>>>(x, xb, rp, edata, We1, be1, bufB);
    mlp_mfma<64, true, false, 0, false><<<MBLK, 256, 0, stream>>>(bufB, W1a, b1a, nullptr, nullptr, outH, nullptr, nullptr);
    mlp_mfma<128, true, true, 1, false><<<MBLK, 256, 0, stream>>>(outH, W1b, b1b, g1, bn1, bufB, h1bf, nullptr);

    // conv2
    conv2_gather<<<WBLK, 256, 0, stream>>>(bufB, (const unsigned*)h1bf, rp, edata, We2, be2, outH);
    mlp_mfma<128, true, false, 0, false><<<MBLK, 256, 0, stream>>>(outH, W2a, b2a, nullptr, nullptr, bufB, nullptr, nullptr);
    // anchor u0 = dis * LN(h2)
    mlp_mfma<128, false, true, 2, true><<<MBLK, 256, 0, stream>>>(bufB, W2b, b2b, g2, bn2, nullptr, (unsigned short*)ancU, dis);

    // compact 4B src stream for APPNP (bufB upper region is free from here on)
    split_kernel<<<EB, 256, 0, stream>>>(edata, esrc);

    // APPNP in u-space: steps 1..15 bf16 ping-pong; step 16 unscales to f32 outH.
    const unsigned* cur = ancU;
    for (int k = 1; k <= K_ITER - 1; k++) {
        unsigned* dstbuf = (k & 1) ? pingA : pingB;
        appnp_step_u<false><<<WBLK2, 256, 0, stream>>>(cur, ancU, dstbuf, nullptr, rp, esrc, selfw, nullptr);
        cur = dstbuf;
    }
    appnp_step_u<true><<<WBLK2, 256, 0, stream>>>(cur, ancU, nullptr, (float2*)outH, rp, esrc, selfw, rsq);

    // pooling on outH
    gate_mfma<<<MBLK, 256, 0, stream>>>(outH, Wg1, bg1, Wg2, bg2, gate);
    seg_begin<<<1, 128, 0, stream>>>(batch, gbeg);
    seg_max<<<N_B, 256, 0, stream>>>(gate, gbeg, gmax);
    seg_sum<<<N_B, 256, 0, stream>>>(gate, gbeg, gmax, gsum);
    hipMemsetAsync(outG, 0, (size_t)N_B * 128 * 4, stream);
    seg_pool<<<N_B * 8, 512, 0, stream>>>(outH, gate, gbeg, gmax, gsum, outG);
}

// Round 6
// 1753.697 us; speedup vs baseline: 1.0482x; 1.0482x over previous
//
#include <hip/hip_runtime.h>
#include <math.h>

#define N_NODES 100000
#define N_EDGES 1600000
#define N_B 64
#define D_IN 64
#define D_HID 128
#define D_OUT 128
#define K_ITER 16
#define LN_EPS 1e-5f

// Binned scatter parameters.
#define BSH 9                       // 512 nodes per bucket
#define NBUCK 196                   // ceil(100000 / 512)
#define NBUCK_PAD 200               // grid modulus for phase B (multiple of 8 -> same-XCD slices)
#define BSPLIT 4                    // slices per bucket in phase B
#define CHUNK 2048                  // edges per phase-A block

typedef short s8v __attribute__((ext_vector_type(8)));
typedef float f4v __attribute__((ext_vector_type(4)));

__device__ __forceinline__ float gelu_f(float x) {
    return 0.5f * x * (1.0f + erff(0.70710678118654752440f * x));
}

__device__ __forceinline__ float ubx(unsigned u) { return __uint_as_float(u << 16); }
__device__ __forceinline__ float uby(unsigned u) { return __uint_as_float(u & 0xffff0000u); }

__device__ __forceinline__ unsigned short bf_rne(float x) {
    unsigned u = __float_as_uint(x);
    u += 0x7fffu + ((u >> 16) & 1u);
    return (unsigned short)(u >> 16);
}
__device__ __forceinline__ float bf_f(unsigned short s) {
    return __uint_as_float(((unsigned)s) << 16);
}
__device__ __forceinline__ unsigned pack_bf2(float a, float b) {
    return (unsigned)bf_rne(a) | (((unsigned)bf_rne(b)) << 16);
}

// ---------------- CSR build ----------------

__global__ __launch_bounds__(256) void hist_kernel(const int* __restrict__ dst, int* __restrict__ counts) {
    int e = blockIdx.x * 256 + threadIdx.x;
    if (e < N_EDGES) atomicAdd(&counts[dst[e]], 1);
}

__global__ __launch_bounds__(256) void deg_kernel(const int* __restrict__ counts,
                                                  float* __restrict__ dis, float* __restrict__ selfw,
                                                  float* __restrict__ rsq) {
    int i = blockIdx.x * 256 + threadIdx.x;
    if (i < N_NODES) {
        float d = (float)(counts[i] + 1);
        dis[i] = 1.0f / sqrtf(d);
        selfw[i] = 1.0f / d;
        rsq[i] = sqrtf(d);
    }
}

__global__ __launch_bounds__(1024) void scan1(const int* __restrict__ counts, int* __restrict__ rp,
                                              int* __restrict__ bsum) {
    __shared__ int tmp[1024];
    int t = threadIdx.x;
    int idx = blockIdx.x * 1024 + t;
    int v = (idx < N_NODES) ? counts[idx] : 0;
    tmp[t] = v;
    __syncthreads();
    for (int o = 1; o < 1024; o <<= 1) {
        int add = (t >= o) ? tmp[t - o] : 0;
        __syncthreads();
        tmp[t] += add;
        __syncthreads();
    }
    if (idx < N_NODES) rp[idx] = tmp[t] - v;   // exclusive
    if (t == 1023) bsum[blockIdx.x] = tmp[t];
}

__global__ void scan2(int* bsum, int nb) {
    if (threadIdx.x == 0 && blockIdx.x == 0) {
        int acc = 0;
        for (int i = 0; i < nb; i++) { int v = bsum[i]; bsum[i] = acc; acc += v; }
    }
}

__global__ __launch_bounds__(1024) void scan3(int* __restrict__ rp, const int* __restrict__ bsum,
                                              int* __restrict__ cursor) {
    int t = threadIdx.x;
    int idx = blockIdx.x * 1024 + t;
    if (idx < N_NODES) {
        int v = rp[idx] + bsum[blockIdx.x];
        rp[idx] = v;
        cursor[idx] = v;
    }
    if (idx == 0) rp[N_NODES] = N_EDGES;
}

// bucket cursors = rp at bucket starts
__global__ void binit(const int* __restrict__ rp, int* __restrict__ bcursor) {
    int b = threadIdx.x;
    if (b < NBUCK) bcursor[b] = rp[b << BSH];
}

// ---------------- Two-phase binned scatter ----------------
// Phase A: bin edges into 196 dst-range buckets. LDS histogram gives in-chunk rank;
// staging + coalesced drain writes each bucket's run contiguously (~10 edges = 167B
// per run -> mostly full 64B lines, vs 16B/line for the naive scatter).
__global__ __launch_bounds__(256) void bin_kernel(const int* __restrict__ src, const int* __restrict__ dst,
                                                  const float* __restrict__ ea,
                                                  int* __restrict__ bcursor, int4* __restrict__ tmp) {
    __shared__ int hist[NBUCK];
    __shared__ int loff[NBUCK];
    __shared__ int gbase[NBUCK];
    __shared__ int total_s;
    __shared__ int4 stage[CHUNK];
    int tid = threadIdx.x;
    int base = blockIdx.x * CHUNK;
    for (int t = tid; t < NBUCK; t += 256) hist[t] = 0;
    __syncthreads();
    int4 rec[8];
    int bk[8], rk[8];
    bool val[8];
    #pragma unroll
    for (int k = 0; k < 8; k++) {
        int e = base + k * 256 + tid;
        val[k] = (e < N_EDGES);
        if (val[k]) {
            int s = src[e], d = dst[e];
            float2 e2 = ((const float2*)ea)[e];
            rec[k].x = s;
            rec[k].y = __float_as_int(e2.x);
            rec[k].z = __float_as_int(e2.y);
            rec[k].w = d;                      // dst rides in the spare slot for phase B
            bk[k] = d >> BSH;
            rk[k] = atomicAdd(&hist[bk[k]], 1);
        }
    }
    __syncthreads();
    if (tid == 0) {
        int acc = 0;
        for (int b = 0; b < NBUCK; b++) { loff[b] = acc; acc += hist[b]; }
        total_s = acc;
    }
    __syncthreads();
    if (tid < NBUCK && hist[tid] > 0) gbase[tid] = atomicAdd(&bcursor[tid], hist[tid]);
    __syncthreads();
    #pragma unroll
    for (int k = 0; k < 8; k++)
        if (val[k]) stage[loff[bk[k]] + rk[k]] = rec[k];
    __syncthreads();
    int total = total_s;
    for (int s = tid; s < total; s += 256) {
        int lo = 0, hi = NBUCK - 1;                 // largest b with loff[b] <= s
        while (lo < hi) {
            int mid = (lo + hi + 1) >> 1;
            if (loff[mid] <= s) lo = mid; else hi = mid - 1;
        }
        tmp[gbase[lo] + (s - loff[lo])] = stage[s];
    }
}

// Phase B: per-bucket scatter to exact CSR positions. All BSPLIT slices of a bucket
// share blockIdx % NBUCK_PAD (NBUCK_PAD % 8 == 0 -> same XCD heuristically), so the
// 64B lines of a bucket's 128KB region fill inside one L2 before eviction.
__global__ __launch_bounds__(256) void scatter2_kernel(const int4* __restrict__ tmp, const int* __restrict__ rp,
                                                       int* __restrict__ cursor, int4* __restrict__ edata) {
    int b = blockIdx.x % NBUCK_PAD;
    int slice = blockIdx.x / NBUCK_PAD;
    if (b >= NBUCK) return;
    int lo = rp[b << BSH];
    int nend = (b + 1) << BSH;
    if (nend > N_NODES) nend = N_NODES;
    int hi = rp[nend];
    for (int i = lo + slice * 256 + threadIdx.x; i < hi; i += BSPLIT * 256) {
        int4 r = tmp[i];
        int pos = atomicAdd(&cursor[r.w], 1);
        edata[pos] = r;
    }
}

// Compact 4B/edge src stream for APPNP (coalesced read+write).
__global__ __launch_bounds__(256) void split_kernel(const int4* __restrict__ edata, int* __restrict__ esrc) {
    int e = blockIdx.x * 256 + threadIdx.x;
    if (e < N_EDGES) esrc[e] = edata[e].x;
}

// x (f32 [N,64]) -> bf16 copy for conv1 message gathers (halves gather bytes).
__global__ __launch_bounds__(256) void x_to_bf(const float4* __restrict__ x4, uint2* __restrict__ xb2) {
    int i = blockIdx.x * 256 + threadIdx.x;
    if (i < N_NODES * 16) {
        float4 v = x4[i];
        uint2 o;
        o.x = pack_bf2(v.x, v.y);
        o.y = pack_bf2(v.z, v.w);
        xb2[i] = o;
    }
}

// ---------------- GINE gathers (round-3 form: full-wave rows, wave-uniform indices) ----------------

// Self term from f32 x; gathered messages from bf16 x copy (128 B/row).
__global__ __launch_bounds__(256) void conv1_gather(const float* __restrict__ x,
                                                    const unsigned short* __restrict__ xb,
                                                    const int* __restrict__ rp,
                                                    const int4* __restrict__ edata,
                                                    const float* __restrict__ We1, const float* __restrict__ be1,
                                                    float* __restrict__ out) {
    int gw = (blockIdx.x * 256 + threadIdx.x) >> 6;
    if (gw >= N_NODES) return;
    int lane = threadIdx.x & 63;
    float w0 = We1[lane], w1 = We1[64 + lane], bb = be1[lane];
    float acc = x[(size_t)gw * 64 + lane];
    int j = rp[gw], jend = rp[gw + 1];
    for (; j + 8 <= jend; j += 8) {
        int4 e0 = edata[j], e1 = edata[j + 1], e2 = edata[j + 2], e3 = edata[j + 3];
        int4 e4 = edata[j + 4], e5 = edata[j + 5], e6 = edata[j + 6], e7 = edata[j + 7];
        unsigned short v0 = xb[(size_t)e0.x * 64 + lane];
        unsigned short v1 = xb[(size_t)e1.x * 64 + lane];
        unsigned short v2 = xb[(size_t)e2.x * 64 + lane];
        unsigned short v3 = xb[(size_t)e3.x * 64 + lane];
        unsigned short v4 = xb[(size_t)e4.x * 64 + lane];
        unsigned short v5 = xb[(size_t)e5.x * 64 + lane];
        unsigned short v6 = xb[(size_t)e6.x * 64 + lane];
        unsigned short v7 = xb[(size_t)e7.x * 64 + lane];
        acc += fmaxf(bf_f(v0) + __int_as_float(e0.y) * w0 + __int_as_float(e0.z) * w1 + bb, 0.0f);
        acc += fmaxf(bf_f(v1) + __int_as_float(e1.y) * w0 + __int_as_float(e1.z) * w1 + bb, 0.0f);
        acc += fmaxf(bf_f(v2) + __int_as_float(e2.y) * w0 + __int_as_float(e2.z) * w1 + bb, 0.0f);
        acc += fmaxf(bf_f(v3) + __int_as_float(e3.y) * w0 + __int_as_float(e3.z) * w1 + bb, 0.0f);
        acc += fmaxf(bf_f(v4) + __int_as_float(e4.y) * w0 + __int_as_float(e4.z) * w1 + bb, 0.0f);
        acc += fmaxf(bf_f(v5) + __int_as_float(e5.y) * w0 + __int_as_float(e5.z) * w1 + bb, 0.0f);
        acc += fmaxf(bf_f(v6) + __int_as_float(e6.y) * w0 + __int_as_float(e6.z) * w1 + bb, 0.0f);
        acc += fmaxf(bf_f(v7) + __int_as_float(e7.y) * w0 + __int_as_float(e7.z) * w1 + bb, 0.0f);
    }
    for (; j < jend; j++) {
        int4 e = edata[j];
        unsigned short v = xb[(size_t)e.x * 64 + lane];
        acc += fmaxf(bf_f(v) + __int_as_float(e.y) * w0 + __int_as_float(e.z) * w1 + bb, 0.0f);
    }
    out[(size_t)gw * 64 + lane] = acc;
}

// conv2: self term from f32 h1, gathered messages from bf16 h1 copy.
__global__ __launch_bounds__(256) void conv2_gather(const float* __restrict__ h1f, const unsigned* __restrict__ h1b,
                                                    const int* __restrict__ rp,
                                                    const int4* __restrict__ edata,
                                                    const float* __restrict__ We2, const float* __restrict__ be2,
                                                    float* __restrict__ out) {
    int gw = (blockIdx.x * 256 + threadIdx.x) >> 6;
    if (gw >= N_NODES) return;
    int lane = threadIdx.x & 63;
    int f0 = lane * 2;
    float w00 = We2[f0], w01 = We2[f0 + 1];
    float w10 = We2[128 + f0], w11 = We2[128 + f0 + 1];
    float b0 = be2[f0], b1 = be2[f0 + 1];
    float2 hc = ((const float2*)h1f)[(size_t)gw * 64 + lane];
    float a0 = hc.x, a1 = hc.y;
    int j = rp[gw], jend = rp[gw + 1];
    for (; j + 8 <= jend; j += 8) {
        int4 e0 = edata[j], e1 = edata[j + 1], e2 = edata[j + 2], e3 = edata[j + 3];
        int4 e4 = edata[j + 4], e5 = edata[j + 5], e6 = edata[j + 6], e7 = edata[j + 7];
        unsigned v0 = h1b[(size_t)e0.x * 64 + lane];
        unsigned v1 = h1b[(size_t)e1.x * 64 + lane];
        unsigned v2 = h1b[(size_t)e2.x * 64 + lane];
        unsigned v3 = h1b[(size_t)e3.x * 64 + lane];
        unsigned v4 = h1b[(size_t)e4.x * 64 + lane];
        unsigned v5 = h1b[(size_t)e5.x * 64 + lane];
        unsigned v6 = h1b[(size_t)e6.x * 64 + lane];
        unsigned v7 = h1b[(size_t)e7.x * 64 + lane];
        a0 += fmaxf(ubx(v0) + __int_as_float(e0.y) * w00 + __int_as_float(e0.z) * w10 + b0, 0.0f);
        a1 += fmaxf(uby(v0) + __int_as_float(e0.y) * w01 + __int_as_float(e0.z) * w11 + b1, 0.0f);
        a0 += fmaxf(ubx(v1) + __int_as_float(e1.y) * w00 + __int_as_float(e1.z) * w10 + b0, 0.0f);
        a1 += fmaxf(uby(v1) + __int_as_float(e1.y) * w01 + __int_as_float(e1.z) * w11 + b1, 0.0f);
        a0 += fmaxf(ubx(v2) + __int_as_float(e2.y) * w00 + __int_as_float(e2.z) * w10 + b0, 0.0f);
        a1 += fmaxf(uby(v2) + __int_as_float(e2.y) * w01 + __int_as_float(e2.z) * w11 + b1, 0.0f);
        a0 += fmaxf(ubx(v3) + __int_as_float(e3.y) * w00 + __int_as_float(e3.z) * w10 + b0, 0.0f);
        a1 += fmaxf(uby(v3) + __int_as_float(e3.y) * w01 + __int_as_float(e3.z) * w11 + b1, 0.0f);
        a0 += fmaxf(ubx(v4) + __int_as_float(e4.y) * w00 + __int_as_float(e4.z) * w10 + b0, 0.0f);
        a1 += fmaxf(uby(v4) + __int_as_float(e4.y) * w01 + __int_as_float(e4.z) * w11 + b1, 0.0f);
        a0 += fmaxf(ubx(v5) + __int_as_float(e5.y) * w00 + __int_as_float(e5.z) * w10 + b0, 0.0f);
        a1 += fmaxf(uby(v5) + __int_as_float(e5.y) * w01 + __int_as_float(e5.z) * w11 + b1, 0.0f);
        a0 += fmaxf(ubx(v6) + __int_as_float(e6.y) * w00 + __int_as_float(e6.z) * w10 + b0, 0.0f);
        a1 += fmaxf(uby(v6) + __int_as_float(e6.y) * w01 + __int_as_float(e6.z) * w11 + b1, 0.0f);
        a0 += fmaxf(ubx(v7) + __int_as_float(e7.y) * w00 + __int_as_float(e7.z) * w10 + b0, 0.0f);
        a1 += fmaxf(uby(v7) + __int_as_float(e7.y) * w01 + __int_as_float(e7.z) * w11 + b1, 0.0f);
    }
    for (; j < jend; j++) {
        int4 e = edata[j];
        unsigned v = h1b[(size_t)e.x * 64 + lane];
        a0 += fmaxf(ubx(v) + __int_as_float(e.y) * w00 + __int_as_float(e.z) * w10 + b0, 0.0f);
        a1 += fmaxf(uby(v) + __int_as_float(e.y) * w01 + __int_as_float(e.z) * w11 + b1, 0.0f);
    }
    out[(size_t)gw * 128 + f0] = a0;
    out[(size_t)gw * 128 + f0 + 1] = a1;
}

// ---------------- MLP layers via MFMA (split-bf16: Ahi*Whi + Ahi*Wlo + Alo*Whi) ----------------
// OMODE: 0 = f32 out only, 1 = f32 + bf16 copy, 2 = bf16 only.
// SCALE: multiply bf16 output by uscale[row] (used to emit u0 = dis*h for APPNP).

template <int Kd, bool GELU, bool LN, int OMODE, bool SCALE>
__global__ __launch_bounds__(256) void mlp_mfma(const float* __restrict__ A, const float* __restrict__ W,
                                                const float* __restrict__ bias, const float* __restrict__ g,
                                                const float* __restrict__ bn, float* __restrict__ outf,
                                                unsigned short* __restrict__ outb,
                                                const float* __restrict__ uscale) {
    __shared__ unsigned short sHi[8192];   // 64 k-rows x 128 cols, swizzled
    __shared__ unsigned short sLo[8192];
    int wave = threadIdx.x >> 6, lane = threadIdx.x & 63;
    int quad = lane >> 4, n = lane & 15;
    int rowA = blockIdx.x * 64 + wave * 16 + n;
    int rowAc = (rowA < N_NODES) ? rowA : 0;

    f4v acc[8];
    #pragma unroll
    for (int t = 0; t < 8; t++) acc[t] = (f4v){0.f, 0.f, 0.f, 0.f};

    for (int ph = 0; ph < Kd / 64; ph++) {
        __syncthreads();
        for (int idx = threadIdx.x; idx < 8192; idx += 256) {
            int k = idx >> 7, c = idx & 127;
            float v = W[(size_t)(ph * 64 + k) * 128 + c];
            unsigned short hi = bf_rne(v);
            unsigned short lo = bf_rne(v - bf_f(hi));
            int kk = k >> 5, q = (k >> 3) & 3, j = k & 7, t = c >> 4, nn = c & 15;
            int lidx = ((((kk * 4 + q) * 8 + t) * 16 + nn) << 3) + j;
            sHi[lidx] = hi;
            sLo[lidx] = lo;
        }
        __syncthreads();
        #pragma unroll
        for (int kk = 0; kk < 2; kk++) {
            int k0 = ph * 64 + kk * 32 + quad * 8;
            const float4* ap = (const float4*)(A + (size_t)rowAc * Kd + k0);
            float4 a0 = ap[0], a1 = ap[1];
            float av[8] = {a0.x, a0.y, a0.z, a0.w, a1.x, a1.y, a1.z, a1.w};
            s8v ahi, alo;
            #pragma unroll
            for (int j = 0; j < 8; j++) {
                unsigned short h = bf_rne(av[j]);
                ahi[j] = (short)h;
                alo[j] = (short)bf_rne(av[j] - bf_f(h));
            }
            int base = ((kk * 4 + quad) * 8) * 128;
            #pragma unroll
            for (int t = 0; t < 8; t++) {
                s8v bhi = *(const s8v*)&sHi[base + ((t * 16 + n) << 3)];
                s8v blo = *(const s8v*)&sLo[base + ((t * 16 + n) << 3)];
                acc[t] = __builtin_amdgcn_mfma_f32_16x16x32_bf16(ahi, bhi, acc[t], 0, 0, 0);
                acc[t] = __builtin_amdgcn_mfma_f32_16x16x32_bf16(ahi, blo, acc[t], 0, 0, 0);
                acc[t] = __builtin_amdgcn_mfma_f32_16x16x32_bf16(alo, bhi, acc[t], 0, 0, 0);
            }
        }
    }

    float bcol[8], gcol[8], bncol[8];
    #pragma unroll
    for (int t = 0; t < 8; t++) {
        bcol[t] = bias[t * 16 + n];
        if (LN) { gcol[t] = g[t * 16 + n]; bncol[t] = bn[t * 16 + n]; }
    }
    #pragma unroll
    for (int r = 0; r < 4; r++) {
        int row = blockIdx.x * 64 + wave * 16 + quad * 4 + r;
        float v[8];
        #pragma unroll
        for (int t = 0; t < 8; t++) {
            float x = acc[t][r] + bcol[t];
            v[t] = GELU ? gelu_f(x) : x;
        }
        if (LN) {
            float s = 0.f, q2 = 0.f;
            #pragma unroll
            for (int t = 0; t < 8; t++) { s += v[t]; q2 += v[t] * v[t]; }
            #pragma unroll
            for (int m = 1; m <= 8; m <<= 1) {
                s += __shfl_xor(s, m, 64);
                q2 += __shfl_xor(q2, m, 64);
            }
            float mu = s * (1.0f / 128.0f);
            float rs = rsqrtf(q2 * (1.0f / 128.0f) - mu * mu + LN_EPS);
            #pragma unroll
            for (int t = 0; t < 8; t++) v[t] = (v[t] - mu) * rs * gcol[t] + bncol[t];
        }
        if (row < N_NODES) {
            float us = SCALE ? uscale[row] : 1.0f;
            #pragma unroll
            for (int t = 0; t < 8; t++) {
                if (OMODE != 2) outf[(size_t)row * 128 + t * 16 + n] = v[t];
                if (OMODE >= 1) outb[(size_t)row * 128 + t * 16 + n] = bf_rne(SCALE ? v[t] * us : v[t]);
            }
        }
    }
}

// ---------------- Gate via MFMA: gate = gelu(h@Wg1+bg1)@Wg2 + bg2 ----------------

__global__ __launch_bounds__(256) void gate_mfma(const float* __restrict__ h, const float* __restrict__ Wg1,
                                                 const float* __restrict__ bg1, const float* __restrict__ Wg2,
                                                 const float* __restrict__ bg2, float* __restrict__ gate) {
    __shared__ unsigned short sHi[8192];  // 128 k x 64 cols, swizzled
    __shared__ unsigned short sLo[8192];
    int wave = threadIdx.x >> 6, lane = threadIdx.x & 63;
    int quad = lane >> 4, n = lane & 15;
    for (int idx = threadIdx.x; idx < 8192; idx += 256) {
        int k = idx >> 6, c = idx & 63;
        float v = Wg1[k * 64 + c];
        unsigned short hi = bf_rne(v);
        unsigned short lo = bf_rne(v - bf_f(hi));
        int kk = k >> 5, q = (k >> 3) & 3, j = k & 7, t = c >> 4, nn = c & 15;
        int lidx = ((((kk * 4 + q) * 4 + t) * 16 + nn) << 3) + j;
        sHi[lidx] = hi;
        sLo[lidx] = lo;
    }
    __syncthreads();
    int rowA = blockIdx.x * 64 + wave * 16 + n;
    int rowAc = (rowA < N_NODES) ? rowA : 0;
    f4v acc[4];
    #pragma unroll
    for (int t = 0; t < 4; t++) acc[t] = (f4v){0.f, 0.f, 0.f, 0.f};
    #pragma unroll
    for (int kk = 0; kk < 4; kk++) {
        const float4* ap = (const float4*)(h + (size_t)rowAc * 128 + kk * 32 + quad * 8);
        float4 a0 = ap[0], a1 = ap[1];
        float av[8] = {a0.x, a0.y, a0.z, a0.w, a1.x, a1.y, a1.z, a1.w};
        s8v ahi, alo;
        #pragma unroll
        for (int j = 0; j < 8; j++) {
            unsigned short hh = bf_rne(av[j]);
            ahi[j] = (short)hh;
            alo[j] = (short)bf_rne(av[j] - bf_f(hh));
        }
        int base = ((kk * 4 + quad) * 4) * 128;
        #pragma unroll
        for (int t = 0; t < 4; t++) {
            s8v bhi = *(const s8v*)&sHi[base + ((t * 16 + n) << 3)];
            s8v blo = *(const s8v*)&sLo[base + ((t * 16 + n) << 3)];
            acc[t] = __builtin_amdgcn_mfma_f32_16x16x32_bf16(ahi, bhi, acc[t], 0, 0, 0);
            acc[t] = __builtin_amdgcn_mfma_f32_16x16x32_bf16(ahi, blo, acc[t], 0, 0, 0);
            acc[t] = __builtin_amdgcn_mfma_f32_16x16x32_bf16(alo, bhi, acc[t], 0, 0, 0);
        }
    }
    float b2 = bg2[0];
    float bb[4], vv[4];
    #pragma unroll
    for (int t = 0; t < 4; t++) { bb[t] = bg1[t * 16 + n]; vv[t] = Wg2[t * 16 + n]; }
    #pragma unroll
    for (int r = 0; r < 4; r++) {
        int row = blockIdx.x * 64 + wave * 16 + quad * 4 + r;
        float val = 0.f;
        #pragma unroll
        for (int t = 0; t < 4; t++) val += gelu_f(acc[t][r] + bb[t]) * vv[t];
        #pragma unroll
        for (int m = 1; m <= 8; m <<= 1) val += __shfl_xor(val, m, 64);
        if (n == 0 && row < N_NODES) gate[row] = val + b2;
    }
}

// ---------------- APPNP in scaled space u = dis*h (round-3 form) ----------------
// u'_i = 0.9*selfw_i*(sum_j u_j + u_i) + 0.1*u0_i ; final h = u*rsq.

template <bool LAST>
__global__ __launch_bounds__(256) void appnp_step_u(const unsigned* __restrict__ hin,
                                                    const unsigned* __restrict__ anchor,
                                                    unsigned* __restrict__ hout, float2* __restrict__ houtf,
                                                    const int* __restrict__ rp, const int* __restrict__ esrc,
                                                    const float* __restrict__ selfw,
                                                    const float* __restrict__ rsq) {
    int gw = (blockIdx.x * 256 + threadIdx.x) >> 6;
    if (gw >= N_NODES) return;
    int lane = threadIdx.x & 63;
    size_t idx = (size_t)gw * 64 + lane;
    unsigned hcp = hin[idx];
    float ax = ubx(hcp), ay = uby(hcp);   // self term (unweighted in u-space)
    int j = rp[gw], jend = rp[gw + 1];
    for (; j + 8 <= jend; j += 8) {
        int s0 = esrc[j],     s1 = esrc[j + 1], s2 = esrc[j + 2], s3 = esrc[j + 3];
        int s4 = esrc[j + 4], s5 = esrc[j + 5], s6 = esrc[j + 6], s7 = esrc[j + 7];
        unsigned v0 = hin[(size_t)s0 * 64 + lane];
        unsigned v1 = hin[(size_t)s1 * 64 + lane];
        unsigned v2 = hin[(size_t)s2 * 64 + lane];
        unsigned v3 = hin[(size_t)s3 * 64 + lane];
        unsigned v4 = hin[(size_t)s4 * 64 + lane];
        unsigned v5 = hin[(size_t)s5 * 64 + lane];
        unsigned v6 = hin[(size_t)s6 * 64 + lane];
        unsigned v7 = hin[(size_t)s7 * 64 + lane];
        ax += ubx(v0); ay += uby(v0);
        ax += ubx(v1); ay += uby(v1);
        ax += ubx(v2); ay += uby(v2);
        ax += ubx(v3); ay += uby(v3);
        ax += ubx(v4); ay += uby(v4);
        ax += ubx(v5); ay += uby(v5);
        ax += ubx(v6); ay += uby(v6);
        ax += ubx(v7); ay += uby(v7);
    }
    for (; j + 4 <= jend; j += 4) {
        int s0 = esrc[j], s1 = esrc[j + 1], s2 = esrc[j + 2], s3 = esrc[j + 3];
        unsigned v0 = hin[(size_t)s0 * 64 + lane];
        unsigned v1 = hin[(size_t)s1 * 64 + lane];
        unsigned v2 = hin[(size_t)s2 * 64 + lane];
        unsigned v3 = hin[(size_t)s3 * 64 + lane];
        ax += ubx(v0); ay += uby(v0);
        ax += ubx(v1); ay += uby(v1);
        ax += ubx(v2); ay += uby(v2);
        ax += ubx(v3); ay += uby(v3);
    }
    for (; j < jend; j++) {
        int s = esrc[j];
        unsigned v = hin[(size_t)s * 64 + lane];
        ax += ubx(v); ay += uby(v);
    }
    float swi = 0.9f * selfw[gw];
    unsigned ancp = anchor[idx];
    float ox = fmaf(swi, ax, 0.1f * ubx(ancp));
    float oy = fmaf(swi, ay, 0.1f * uby(ancp));
    if (LAST) {
        float rq = rsq[gw];
        float2 o; o.x = ox * rq; o.y = oy * rq;
        houtf[idx] = o;
    } else {
        hout[idx] = pack_bf2(ox, oy);
    }
}

// ---------------- Attentional pooling ----------------

__global__ void seg_begin(const int* __restrict__ batch, int* __restrict__ gbeg) {
    int b = threadIdx.x;
    if (b > N_B) return;
    if (b == N_B) { gbeg[N_B] = N_NODES; return; }
    int lo = 0, hi = N_NODES;
    while (lo < hi) {
        int mid = (lo + hi) >> 1;
        if (batch[mid] < b) lo = mid + 1; else hi = mid;
    }
    gbeg[b] = lo;
}

__global__ __launch_bounds__(256) void seg_max(const float* __restrict__ gate, const int* __restrict__ gbeg,
                                               float* __restrict__ gmax) {
    int b = blockIdx.x;
    int s = gbeg[b], e = gbeg[b + 1];
    float m = -INFINITY;
    for (int i = s + threadIdx.x; i < e; i += 256) m = fmaxf(m, gate[i]);
    for (int o = 32; o > 0; o >>= 1) m = fmaxf(m, __shfl_xor(m, o, 64));
    __shared__ float red[4];
    if ((threadIdx.x & 63) == 0) red[threadIdx.x >> 6] = m;
    __syncthreads();
    if (threadIdx.x == 0) gmax[b] = fmaxf(fmaxf(red[0], red[1]), fmaxf(red[2], red[3]));
}

__global__ __launch_bounds__(256) void seg_sum(const float* __restrict__ gate, const int* __restrict__ gbeg,
                                               const float* __restrict__ gmax, float* __restrict__ gsum) {
    int b = blockIdx.x;
    int s = gbeg[b], e = gbeg[b + 1];
    float m = gmax[b];
    float acc = 0.0f;
    for (int i = s + threadIdx.x; i < e; i += 256) acc += expf(gate[i] - m);
    for (int o = 32; o > 0; o >>= 1) acc += __shfl_xor(acc, o, 64);
    __shared__ float red[4];
    if ((threadIdx.x & 63) == 0) red[threadIdx.x >> 6] = acc;
    __syncthreads();
    if (threadIdx.x == 0) gsum[b] = red[0] + red[1] + red[2] + red[3];
}

// 8 slices per graph; atomicAdd into zero-initialized gout.
__global__ __launch_bounds__(512) void seg_pool(const float* __restrict__ h, const float* __restrict__ gate,
                                                const int* __restrict__ gbeg, const float* __restrict__ gmax,
                                                const float* __restrict__ gsum, float* __restrict__ gout) {
    int b = blockIdx.x >> 3, slice = blockIdx.x & 7;
    int team = threadIdx.x >> 7;
    int f = threadIdx.x & 127;
    int s = gbeg[b], e = gbeg[b + 1];
    float m = gmax[b];
    float inv = (e > s) ? 1.0f / gsum[b] : 0.0f;
    float acc = 0.0f;
    for (int i = s + slice * 4 + team; i < e; i += 32) {
        float a = expf(gate[i] - m) * inv;
        acc = fmaf(a, h[(size_t)i * 128 + f], acc);
    }
    __shared__ float red[4][128];
    red[team][f] = acc;
    __syncthreads();
    if (team == 0) {
        float v = red[0][f] + red[1][f] + red[2][f] + red[3][f];
        atomicAdd(&gout[b * 128 + f], v);
    }
}

// ---------------- host launch ----------------

extern "C" void kernel_launch(void* const* d_in, const int* in_sizes, int n_in,
                              void* d_out, int out_size, void* d_ws, size_t ws_size,
                              hipStream_t stream) {
    const float* x     = (const float*)d_in[0];
    const int*   ei    = (const int*)d_in[1];
    const int*   batch = (const int*)d_in[2];
    const float* ea    = (const float*)d_in[3];
    const float* We1 = (const float*)d_in[4];
    const float* be1 = (const float*)d_in[5];
    const float* W1a = (const float*)d_in[6];
    const float* b1a = (const float*)d_in[7];
    const float* W1b = (const float*)d_in[8];
    const float* b1b = (const float*)d_in[9];
    const float* g1  = (const float*)d_in[10];
    const float* bn1 = (const float*)d_in[11];
    const float* We2 = (const float*)d_in[12];
    const float* be2 = (const float*)d_in[13];
    const float* W2a = (const float*)d_in[14];
    const float* b2a = (const float*)d_in[15];
    const float* W2b = (const float*)d_in[16];
    const float* b2b = (const float*)d_in[17];
    const float* g2  = (const float*)d_in[18];
    const float* bn2 = (const float*)d_in[19];
    const float* Wg1 = (const float*)d_in[20];
    const float* bg1 = (const float*)d_in[21];
    const float* Wg2 = (const float*)d_in[22];
    const float* bg2 = (const float*)d_in[23];

    float* outH = (float*)d_out;                 // [N,128] final h (also used as scratch)
    float* outG = outH + (size_t)N_NODES * 128;  // [B,128] pooled

    char* w = (char*)d_ws;
    auto carve = [&](size_t bytes) {
        void* p = (void*)w;
        w += ((bytes + 255) / 256) * 256;
        return p;
    };
    float*  bufB   = (float*)carve((size_t)N_NODES * 128 * 4);  // 51.2 MB
    float*  bufC   = (float*)carve((size_t)N_NODES * 128 * 4);  // 51.2 MB
    int4*   edata  = (int4*)carve((size_t)N_EDGES * 16);        // 25.6 MB {src, ea.x, ea.y, dst}
    int*    counts = (int*)carve((size_t)N_NODES * 4);
    int*    rp     = (int*)carve((size_t)(N_NODES + 1) * 4);
    int*    cursor = (int*)carve((size_t)N_NODES * 4);
    float*  dis    = (float*)carve((size_t)N_NODES * 4);
    float*  selfw  = (float*)carve((size_t)N_NODES * 4);
    float*  rsq    = (float*)carve((size_t)N_NODES * 4);
    float*  gate   = (float*)carve((size_t)N_NODES * 4);
    int*    bsum   = (int*)carve(128 * 4);
    int*    bcursor= (int*)carve(NBUCK_PAD * 4);
    float*  gmax   = (float*)carve(N_B * 4);
    float*  gsum   = (float*)carve(N_B * 4);
    int*    gbeg   = (int*)carve((N_B + 1) * 4);

    const int* src = ei;
    const int* dst = ei + N_EDGES;

    const int NB_SCAN = (N_NODES + 1023) / 1024;  // 98
    const int EB = (N_EDGES + 255) / 256;
    const int NBLK = (N_NODES + 255) / 256;
    const int WBLK = (N_NODES + 3) / 4;    // one wave per node, 4 waves/block
    const int MBLK = (N_NODES + 63) / 64;  // 1563 blocks for mfma kernels
    const int ABLK = (N_EDGES + CHUNK - 1) / CHUNK;  // 782 phase-A blocks

    // Buffer plan (liveness):
    //   tmp (binned edges) = bufB[0:25.6MB] (dead before conv1 writes bufB)
    //   xb (bf16 x copy) = bufC[25.6:38.4MB] (pingA region; dead until APPNP)
    //   agg1 = bufB ; t1 = outH ; h1f = bufB (overwrites agg1), h1bf = bufC[0:25.6MB]
    //   agg2 = outH (overwrites t1) ; t2 = bufB (overwrites h1f)
    //   anchor u0 = bufC[0:25.6] (overwrites h1bf) ; pingA = bufC[25.6:51.2] ; pingB = bufB[0:25.6]
    //   esrc = bufB[25.6:32.0] (written by split_kernel after mlp2b reads bufB)
    unsigned short* h1bf  = (unsigned short*)bufC;
    unsigned* ancU  = (unsigned*)bufC;
    unsigned* pingA = ancU + (size_t)N_NODES * 64;
    unsigned* pingB = (unsigned*)bufB;
    unsigned short* xb = (unsigned short*)pingA;   // [N,64] bf16, dead before APPNP starts
    int*      esrc  = (int*)(bufB + (size_t)N_NODES * 64);
    int4*     tmp   = (int4*)bufB;                 // binned edges, dead before conv1

    // CSR build
    hipMemsetAsync(counts, 0, (size_t)N_NODES * 4, stream);
    hist_kernel<<<EB, 256, 0, stream>>>(dst, counts);
    deg_kernel<<<NBLK, 256, 0, stream>>>(counts, dis, selfw, rsq);
    scan1<<<NB_SCAN, 1024, 0, stream>>>(counts, rp, bsum);
    scan2<<<1, 64, 0, stream>>>(bsum, NB_SCAN);
    scan3<<<NB_SCAN, 1024, 0, stream>>>(rp, bsum, cursor);
    binit<<<1, 256, 0, stream>>>(rp, bcursor);
    bin_kernel<<<ABLK, 256, 0, stream>>>(src, dst, ea, bcursor, tmp);
    scatter2_kernel<<<NBUCK_PAD * BSPLIT, 256, 0, stream>>>(tmp, rp, cursor, edata);
    x_to_bf<<<(N_NODES * 16 + 255) / 256, 256, 0, stream>>>((const float4*)x, (uint2*)xb);

    // conv1
    conv1_gather<<<WBLK, 256, 0, stream>>>(x, xb, rp, edata, We1, be1, bufB);
    mlp_mfma<64, true, false, 0, false><<<MBLK, 256, 0, stream>>>(bufB, W1a, b1a, nullptr, nullptr, outH, nullptr, nullptr);
    mlp_mfma<128, true, true, 1, false><<<MBLK, 256, 0, stream>>>(outH, W1b, b1b, g1, bn1, bufB, h1bf, nullptr);

    // conv2
    conv2_gather<<<WBLK, 256, 0, stream>>>(bufB, (const unsigned*)h1bf, rp, edata, We2, be2, outH);
    mlp_mfma<128, true, false, 0, false><<<MBLK, 256, 0, stream>>>(outH, W2a, b2a, nullptr, nullptr, bufB, nullptr, nullptr);
    // anchor u0 = dis * LN(h2)
    mlp_mfma<128, false, true, 2, true><<<MBLK, 256, 0, stream>>>(bufB, W2b, b2b, g2, bn2, nullptr, (unsigned short*)ancU, dis);

    // compact 4B src stream for APPNP (bufB upper region is free from here on)
    split_kernel<<<EB, 256, 0, stream>>>(edata, esrc);

    // APPNP in u-space: steps 1..15 bf16 ping-pong; step 16 unscales to f32 outH.
    const unsigned* cur = ancU;
    for (int k = 1; k <= K_ITER - 1; k++) {
        unsigned* dstbuf = (k & 1) ? pingA : pingB;
        appnp_step_u<false><<<WBLK, 256, 0, stream>>>(cur, ancU, dstbuf, nullptr, rp, esrc, selfw, nullptr);
        cur = dstbuf;
    }
    appnp_step_u<true><<<WBLK, 256, 0, stream>>>(cur, ancU, nullptr, (float2*)outH, rp, esrc, selfw, rsq);

    // pooling on outH
    gate_mfma<<<MBLK, 256, 0, stream>>>(outH, Wg1, bg1, Wg2, bg2, gate);
    seg_begin<<<1, 128, 0, stream>>>(batch, gbeg);
    seg_max<<<N_B, 256, 0, stream>>>(gate, gbeg, gmax);
    seg_sum<<<N_B, 256, 0, stream>>>(gate, gbeg, gmax, gsum);
    hipMemsetAsync(outG, 0, (size_t)N_B * 128 * 4, stream);
    seg_pool<<<N_B * 8, 512, 0, stream>>>(outH, gate, gbeg, gmax, gsum, outG);
}